// Round 4
// baseline (1061.558 us; speedup 1.0000x reference)
//
#include <hip/hip_runtime.h>

// MultiClassDiceLoss: labels {1,2,3}, float32 vols with values in {0,1,2,3}.
// dice_l = 2*|A_l & B_l| / (|A_l| + |B_l| + eps); out = 1 - mean(dice_l).
// One-pass read of 2 x 512 MiB. History:
//  R1 grid-stride:            ~415 us (2.6 TB/s eff)  latency-bound
//  R3 block-linear+nt+8-deep: ~324 us (3.3 TB/s eff)  but in-flight drains
//     to 0 each iteration (loads -> barrier -> compute -> repeat).
//  R4: steady-state 2-stage software pipeline: prefetch next 4 dwordx4
//      during current compute; __launch_bounds__(256,8) keeps VGPR<=64 so
//      all 32 waves/CU stay resident.

#define NCNT 9   // c1[1..3], c2[1..3], inter[1..3]

typedef float v4f __attribute__((ext_vector_type(4)));

__global__ void dice_zero_ws(unsigned int* counters) {
    int i = threadIdx.x;
    if (i < NCNT) counters[i] = 0u;
}

__device__ __forceinline__ void count4(v4f x, v4f y, unsigned int* c) {
#pragma unroll
    for (int comp = 0; comp < 4; ++comp) {
        float xa = x[comp];
        float yb = y[comp];
        bool a1 = (xa == 1.0f), a2 = (xa == 2.0f), a3 = (xa == 3.0f);
        bool b1 = (yb == 1.0f), b2 = (yb == 2.0f), b3 = (yb == 3.0f);
        c[0] += a1; c[1] += a2; c[2] += a3;
        c[3] += b1; c[4] += b2; c[5] += b3;
        c[6] += a1 & b1; c[7] += a2 & b2; c[8] += a3 & b3;
    }
}

__global__ __launch_bounds__(256, 8) void dice_count(const v4f* __restrict__ a,
                                                     const v4f* __restrict__ b,
                                                     unsigned int* __restrict__ counters,
                                                     int n4) {
    unsigned int c[NCNT];
#pragma unroll
    for (int k = 0; k < NCNT; ++k) c[k] = 0u;

    const int T = 256;                       // blockDim.x
    const int STEP = 2 * T;                  // 2 v4f per volume per thread per iter
    // block-linear: contiguous chunk per block, multiple of STEP
    const int per_block = (n4 / gridDim.x) & ~(STEP - 1);
    const int base = blockIdx.x * per_block;
    const int iters = per_block / STEP;

    int i = base + (int)threadIdx.x;

    // pipeline prologue: first 4 loads in flight
    v4f x0 = __builtin_nontemporal_load(&a[i]);
    v4f x1 = __builtin_nontemporal_load(&a[i + T]);
    v4f y0 = __builtin_nontemporal_load(&b[i]);
    v4f y1 = __builtin_nontemporal_load(&b[i + T]);

    for (int it = 1; it < iters; ++it) {
        const int j = i + STEP;
        // issue next iteration's 4 loads BEFORE consuming current ones:
        v4f nx0 = __builtin_nontemporal_load(&a[j]);
        v4f nx1 = __builtin_nontemporal_load(&a[j + T]);
        v4f ny0 = __builtin_nontemporal_load(&b[j]);
        v4f ny1 = __builtin_nontemporal_load(&b[j + T]);
        __builtin_amdgcn_sched_barrier(0);   // keep prefetch above compute
        count4(x0, y0, c);
        count4(x1, y1, c);
        x0 = nx0; x1 = nx1; y0 = ny0; y1 = ny1;
        i = j;
    }
    count4(x0, y0, c);
    count4(x1, y1, c);

    // remainder (empty for 512^3 with 2048 blocks; kept for generality)
    const int done = per_block * gridDim.x;
    for (int r = done + blockIdx.x * T + (int)threadIdx.x; r < n4;
         r += gridDim.x * T) {
        count4(a[r], b[r], c);
    }

    // wave-level reduction (wave = 64 lanes)
#pragma unroll
    for (int k = 0; k < NCNT; ++k) {
#pragma unroll
        for (int off = 32; off > 0; off >>= 1)
            c[k] += __shfl_down(c[k], off, 64);
    }

    __shared__ unsigned int s[4][NCNT];  // 256 threads -> 4 waves
    const int wave = threadIdx.x >> 6;
    const int lane = threadIdx.x & 63;
    if (lane == 0) {
#pragma unroll
        for (int k = 0; k < NCNT; ++k) s[wave][k] = c[k];
    }
    __syncthreads();
    if (threadIdx.x == 0) {
#pragma unroll
        for (int k = 0; k < NCNT; ++k) {
            unsigned int v = s[0][k] + s[1][k] + s[2][k] + s[3][k];
            atomicAdd(&counters[k], v);
        }
    }
}

__global__ void dice_finalize(const unsigned int* __restrict__ counters,
                              float* __restrict__ out) {
    const double eps = 1.1920928955078125e-07;  // np.float32 eps
    double acc = 0.0;
#pragma unroll
    for (int l = 0; l < 3; ++l) {
        double c1 = (double)counters[l];
        double c2 = (double)counters[3 + l];
        double in = (double)counters[6 + l];
        acc += (2.0 * in) / (c1 + c2 + eps);
    }
    out[0] = (float)(1.0 - acc / 3.0);
}

extern "C" void kernel_launch(void* const* d_in, const int* in_sizes, int n_in,
                              void* d_out, int out_size, void* d_ws, size_t ws_size,
                              hipStream_t stream) {
    const float* v1 = (const float*)d_in[0];
    const float* v2 = (const float*)d_in[1];
    float* out = (float*)d_out;
    unsigned int* counters = (unsigned int*)d_ws;

    const int n = in_sizes[0];        // 512^3 = 134217728, divisible by 4
    const int n4 = n >> 2;

    dice_zero_ws<<<1, 64, 0, stream>>>(counters);

    const int threads = 256;
    const int blocks = 2048;          // 8 blocks/CU (pinned by launch_bounds)
    dice_count<<<blocks, threads, 0, stream>>>(
        (const v4f*)v1, (const v4f*)v2, counters, n4);

    dice_finalize<<<1, 1, 0, stream>>>(counters, out);
}

// Round 5
// 1058.042 us; speedup vs baseline: 1.0033x; 1.0033x over previous
//
#include <hip/hip_runtime.h>

// MultiClassDiceLoss: labels {1,2,3}, float32 vols with values in {0,1,2,3}.
// dice_l = 2*|A_l & B_l| / (|A_l| + |B_l| + eps); out = 1 - mean(dice_l).
// One-pass read of 2 x 512 MiB. History:
//  R1 grid-stride, 2-deep:      ~415 us (2.6 TB/s eff)  MLP-starved
//  R3 block-linear+nt+8-deep:   ~324 us (3.3 TB/s eff)
//  R4 +2-stage pipeline:        ~340 us  NEUTRAL -> not latency/MLP-bound;
//     queue-saturated service-rate wall.
//  R5 theory: all blocks start 256KiB-aligned chunks at j=0 -> instantaneous
//     HBM channel coverage ~6% (lockstep phase). Fix: per-block iteration
//     phase rotation (block k starts at iter k mod iters, wraps) -> uniform
//     instantaneous channel coverage. Everything else identical to R3.

#define NCNT 9   // c1[1..3], c2[1..3], inter[1..3]
#define UNROLL 4

typedef float v4f __attribute__((ext_vector_type(4)));

__global__ void dice_zero_ws(unsigned int* counters) {
    int i = threadIdx.x;
    if (i < NCNT) counters[i] = 0u;
}

__device__ __forceinline__ void count4(v4f x, v4f y, unsigned int* c) {
#pragma unroll
    for (int comp = 0; comp < 4; ++comp) {
        float xa = x[comp];
        float yb = y[comp];
        bool a1 = (xa == 1.0f), a2 = (xa == 2.0f), a3 = (xa == 3.0f);
        bool b1 = (yb == 1.0f), b2 = (yb == 2.0f), b3 = (yb == 3.0f);
        c[0] += a1; c[1] += a2; c[2] += a3;
        c[3] += b1; c[4] += b2; c[5] += b3;
        c[6] += a1 & b1; c[7] += a2 & b2; c[8] += a3 & b3;
    }
}

__device__ __forceinline__ void body8(const v4f* __restrict__ a,
                                      const v4f* __restrict__ b,
                                      int i, int T, unsigned int* c) {
    v4f x0 = __builtin_nontemporal_load(&a[i]);
    v4f x1 = __builtin_nontemporal_load(&a[i + T]);
    v4f x2 = __builtin_nontemporal_load(&a[i + 2 * T]);
    v4f x3 = __builtin_nontemporal_load(&a[i + 3 * T]);
    v4f y0 = __builtin_nontemporal_load(&b[i]);
    v4f y1 = __builtin_nontemporal_load(&b[i + T]);
    v4f y2 = __builtin_nontemporal_load(&b[i + 2 * T]);
    v4f y3 = __builtin_nontemporal_load(&b[i + 3 * T]);
    // keep all 8 global_load_dwordx4 issued before any consumption
    __builtin_amdgcn_sched_barrier(0);
    count4(x0, y0, c);
    count4(x1, y1, c);
    count4(x2, y2, c);
    count4(x3, y3, c);
}

__global__ __launch_bounds__(256) void dice_count(const v4f* __restrict__ a,
                                                  const v4f* __restrict__ b,
                                                  unsigned int* __restrict__ counters,
                                                  int n4) {
    unsigned int c[NCNT];
#pragma unroll
    for (int k = 0; k < NCNT; ++k) c[k] = 0u;

    const int T = 256;                       // blockDim.x
    const int STEP = T * UNROLL;             // v4f elements per block-iteration
    // block-linear: contiguous chunk per block, multiple of STEP
    const int per_block = (n4 / gridDim.x) & ~(STEP - 1);
    const int base = blockIdx.x * per_block;
    const int iters = per_block / STEP;
    // phase rotation: decorrelate HBM channel phase across blocks
    const int rot = (iters > 0) ? ((int)blockIdx.x % iters) : 0;

    for (int j = rot; j < iters; ++j)
        body8(a, b, base + j * STEP + (int)threadIdx.x, T, c);
    for (int j = 0; j < rot; ++j)
        body8(a, b, base + j * STEP + (int)threadIdx.x, T, c);

    // remainder (empty for 512^3 with 2048 blocks; kept for generality)
    const int done = per_block * gridDim.x;
    for (int r = done + blockIdx.x * T + (int)threadIdx.x; r < n4;
         r += gridDim.x * T) {
        count4(a[r], b[r], c);
    }

    // wave-level reduction (wave = 64 lanes)
#pragma unroll
    for (int k = 0; k < NCNT; ++k) {
#pragma unroll
        for (int off = 32; off > 0; off >>= 1)
            c[k] += __shfl_down(c[k], off, 64);
    }

    __shared__ unsigned int s[4][NCNT];  // 256 threads -> 4 waves
    const int wave = threadIdx.x >> 6;
    const int lane = threadIdx.x & 63;
    if (lane == 0) {
#pragma unroll
        for (int k = 0; k < NCNT; ++k) s[wave][k] = c[k];
    }
    __syncthreads();
    if (threadIdx.x == 0) {
#pragma unroll
        for (int k = 0; k < NCNT; ++k) {
            unsigned int v = s[0][k] + s[1][k] + s[2][k] + s[3][k];
            atomicAdd(&counters[k], v);
        }
    }
}

__global__ void dice_finalize(const unsigned int* __restrict__ counters,
                              float* __restrict__ out) {
    const double eps = 1.1920928955078125e-07;  // np.float32 eps
    double acc = 0.0;
#pragma unroll
    for (int l = 0; l < 3; ++l) {
        double c1 = (double)counters[l];
        double c2 = (double)counters[3 + l];
        double in = (double)counters[6 + l];
        acc += (2.0 * in) / (c1 + c2 + eps);
    }
    out[0] = (float)(1.0 - acc / 3.0);
}

extern "C" void kernel_launch(void* const* d_in, const int* in_sizes, int n_in,
                              void* d_out, int out_size, void* d_ws, size_t ws_size,
                              hipStream_t stream) {
    const float* v1 = (const float*)d_in[0];
    const float* v2 = (const float*)d_in[1];
    float* out = (float*)d_out;
    unsigned int* counters = (unsigned int*)d_ws;

    const int n = in_sizes[0];        // 512^3 = 134217728, divisible by 4
    const int n4 = n >> 2;

    dice_zero_ws<<<1, 64, 0, stream>>>(counters);

    const int threads = 256;
    const int blocks = 2048;          // 256 KiB chunk per block per volume
    dice_count<<<blocks, threads, 0, stream>>>(
        (const v4f*)v1, (const v4f*)v2, counters, n4);

    dice_finalize<<<1, 1, 0, stream>>>(counters, out);
}

// Round 6
// 1049.813 us; speedup vs baseline: 1.0112x; 1.0078x over previous
//
#include <hip/hip_runtime.h>

// MultiClassDiceLoss: labels {1,2,3}, float32 vols with values in {0,1,2,3}.
// dice_l = 2*|A_l & B_l| / (|A_l| + |B_l| + eps); out = 1 - mean(dice_l).
// One-pass read of 2 x 512 MiB. History:
//  R1 grid-stride, 2-deep:       ~415 us (2.6 TB/s eff)  MLP-starved
//  R2 grid-stride, 4x unroll:    ~400 us (compiler collapsed window, VGPR=28)
//  R3 block-linear+nt+8-deep:    ~324 us (3.3 TB/s eff)
//  R4 software pipeline:         neutral -> not latency-bound
//  R5 phase rotation:            neutral -> not channel-phase
//  R6 theory: R3's 4096 slow fronts (2048 blocks x 2 vols, private 256 KiB
//     chunks) thrash DRAM row buffers; fill/copy kernels reach 6.5 TB/s with
//     ONE dense front per buffer (grid-stride). Fix: block-contiguous 16 KiB
//     chunk advancing by GRID stride (2 dense fronts total) + keep the
//     forced 8-deep nt load window.

#define NCNT 9   // c1[1..3], c2[1..3], inter[1..3]
#define UNROLL 4

typedef float v4f __attribute__((ext_vector_type(4)));

__global__ void dice_zero_ws(unsigned int* counters) {
    int i = threadIdx.x;
    if (i < NCNT) counters[i] = 0u;
}

__device__ __forceinline__ void count4(v4f x, v4f y, unsigned int* c) {
#pragma unroll
    for (int comp = 0; comp < 4; ++comp) {
        float xa = x[comp];
        float yb = y[comp];
        bool a1 = (xa == 1.0f), a2 = (xa == 2.0f), a3 = (xa == 3.0f);
        bool b1 = (yb == 1.0f), b2 = (yb == 2.0f), b3 = (yb == 3.0f);
        c[0] += a1; c[1] += a2; c[2] += a3;
        c[3] += b1; c[4] += b2; c[5] += b3;
        c[6] += a1 & b1; c[7] += a2 & b2; c[8] += a3 & b3;
    }
}

__device__ __forceinline__ void body8(const v4f* __restrict__ a,
                                      const v4f* __restrict__ b,
                                      int i, int T, unsigned int* c) {
    v4f x0 = __builtin_nontemporal_load(&a[i]);
    v4f x1 = __builtin_nontemporal_load(&a[i + T]);
    v4f x2 = __builtin_nontemporal_load(&a[i + 2 * T]);
    v4f x3 = __builtin_nontemporal_load(&a[i + 3 * T]);
    v4f y0 = __builtin_nontemporal_load(&b[i]);
    v4f y1 = __builtin_nontemporal_load(&b[i + T]);
    v4f y2 = __builtin_nontemporal_load(&b[i + 2 * T]);
    v4f y3 = __builtin_nontemporal_load(&b[i + 3 * T]);
    // keep all 8 global_load_dwordx4 issued before any consumption
    __builtin_amdgcn_sched_barrier(0);
    count4(x0, y0, c);
    count4(x1, y1, c);
    count4(x2, y2, c);
    count4(x3, y3, c);
}

__global__ __launch_bounds__(256) void dice_count(const v4f* __restrict__ a,
                                                  const v4f* __restrict__ b,
                                                  unsigned int* __restrict__ counters,
                                                  int n4) {
    unsigned int c[NCNT];
#pragma unroll
    for (int k = 0; k < NCNT; ++k) c[k] = 0u;

    const int T = 256;                   // blockDim.x
    const int CHUNK = T * UNROLL;        // 1024 v4f = 16 KiB per block-iter
    const int gstride = gridDim.x * CHUNK;   // whole-grid slab: 32 MiB @2048
    // portion evenly covered by whole-grid slabs:
    const int nfull = (n4 / gstride) * gstride;

    for (int i = blockIdx.x * CHUNK + (int)threadIdx.x; i < nfull; i += gstride)
        body8(a, b, i, T, c);

    // remainder (empty for 512^3 with 2048 blocks; kept for generality)
    for (int r = nfull + blockIdx.x * T + (int)threadIdx.x; r < n4;
         r += gridDim.x * T) {
        count4(a[r], b[r], c);
    }

    // wave-level reduction (wave = 64 lanes)
#pragma unroll
    for (int k = 0; k < NCNT; ++k) {
#pragma unroll
        for (int off = 32; off > 0; off >>= 1)
            c[k] += __shfl_down(c[k], off, 64);
    }

    __shared__ unsigned int s[4][NCNT];  // 256 threads -> 4 waves
    const int wave = threadIdx.x >> 6;
    const int lane = threadIdx.x & 63;
    if (lane == 0) {
#pragma unroll
        for (int k = 0; k < NCNT; ++k) s[wave][k] = c[k];
    }
    __syncthreads();
    if (threadIdx.x == 0) {
#pragma unroll
        for (int k = 0; k < NCNT; ++k) {
            unsigned int v = s[0][k] + s[1][k] + s[2][k] + s[3][k];
            atomicAdd(&counters[k], v);
        }
    }
}

__global__ void dice_finalize(const unsigned int* __restrict__ counters,
                              float* __restrict__ out) {
    const double eps = 1.1920928955078125e-07;  // np.float32 eps
    double acc = 0.0;
#pragma unroll
    for (int l = 0; l < 3; ++l) {
        double c1 = (double)counters[l];
        double c2 = (double)counters[3 + l];
        double in = (double)counters[6 + l];
        acc += (2.0 * in) / (c1 + c2 + eps);
    }
    out[0] = (float)(1.0 - acc / 3.0);
}

extern "C" void kernel_launch(void* const* d_in, const int* in_sizes, int n_in,
                              void* d_out, int out_size, void* d_ws, size_t ws_size,
                              hipStream_t stream) {
    const float* v1 = (const float*)d_in[0];
    const float* v2 = (const float*)d_in[1];
    float* out = (float*)d_out;
    unsigned int* counters = (unsigned int*)d_ws;

    const int n = in_sizes[0];        // 512^3 = 134217728, divisible by 4
    const int n4 = n >> 2;

    dice_zero_ws<<<1, 64, 0, stream>>>(counters);

    const int threads = 256;
    const int blocks = 2048;          // 8 blocks/CU; 16 KiB chunk per iter
    dice_count<<<blocks, threads, 0, stream>>>(
        (const v4f*)v1, (const v4f*)v2, counters, n4);

    dice_finalize<<<1, 1, 0, stream>>>(counters, out);
}